// Round 1
// baseline (7454.436 us; speedup 1.0000x reference)
//
#include <hip/hip_runtime.h>
#include <math.h>

// SmallSwitchTransformer forward, fp32 baseline.
// Key algebraic optimization vs reference: MoE computes only the routed
// (top-1) expert per token instead of all 8 (identical result: the dense
// reference multiplies by a one-hot mask).
//
// Workspace layout (floats):
//   x[T*H] | qkv[T*3H] | scores[B*NH*S*S] | attno[T*H] | hid[T*FF] |
//   moe[T*H] | probs[T*E] | gate[T] | lbacc[1] | cnt[E](int) | toklist[E*T](int)
// Total ~151 MB.

constexpr int CB = 8;      // batch
constexpr int CS = 512;    // seq
constexpr int CH = 512;    // hidden
constexpr int CNH = 8;     // heads
constexpr int CDH = 64;    // head dim
constexpr int CE = 8;      // experts
constexpr int CFF = 2048;  // ffn dim
constexpr int CL = 6;      // layers
constexpr int CV = 32000;  // vocab
constexpr int CT = CB * CS;   // 4096 tokens
constexpr int CH3 = 3 * CH;   // 1536

// ---------------------------------------------------------------- init
__global__ __launch_bounds__(64) void k_init(int* cnt, float* lbacc) {
  int tid = threadIdx.x;
  if (tid < CE) cnt[tid] = 0;
  if (tid == 0) *lbacc = 0.f;
}

// ---------------------------------------------------------------- embedding
__global__ __launch_bounds__(256) void k_embed(const int* __restrict__ ids,
                                               const float* __restrict__ emb,
                                               const float* __restrict__ pos,
                                               float* __restrict__ x) {
  int i = blockIdx.x * 256 + threadIdx.x;  // float4 index over CT*CH/4
  int t = i / (CH / 4);
  int h4 = i % (CH / 4);
  int id = ids[t];
  float4 e = ((const float4*)(emb + (size_t)id * CH))[h4];
  float4 p = ((const float4*)(pos + (size_t)(t % CS) * CH))[h4];
  float4 r;
  r.x = e.x + p.x; r.y = e.y + p.y; r.z = e.z + p.z; r.w = e.w + p.w;
  ((float4*)(x + (size_t)t * CH))[h4] = r;
}

// ---------------------------------------------------------------- GEMM: C = A @ W^T + bias
// A[M,K], W[N,K], C[M,N]. M,N multiples of 64; K multiple of 16.
__global__ __launch_bounds__(256) void k_gemm_bt(const float* __restrict__ A,
                                                 const float* __restrict__ W,
                                                 const float* __restrict__ bias,
                                                 float* __restrict__ C,
                                                 int N, int K) {
  __shared__ __align__(16) float As[16][64];
  __shared__ __align__(16) float Ws[16][64];
  int tid = threadIdx.x;
  int m0 = blockIdx.y * 64, n0 = blockIdx.x * 64;
  int lr = tid >> 2, lk = (tid & 3) << 2;
  int tx = tid & 15, ty = tid >> 4;
  float acc[4][4] = {};
  for (int k0 = 0; k0 < K; k0 += 16) {
    float4 a = *(const float4*)(A + (size_t)(m0 + lr) * K + k0 + lk);
    float4 w = *(const float4*)(W + (size_t)(n0 + lr) * K + k0 + lk);
    As[lk + 0][lr] = a.x; As[lk + 1][lr] = a.y; As[lk + 2][lr] = a.z; As[lk + 3][lr] = a.w;
    Ws[lk + 0][lr] = w.x; Ws[lk + 1][lr] = w.y; Ws[lk + 2][lr] = w.z; Ws[lk + 3][lr] = w.w;
    __syncthreads();
#pragma unroll
    for (int kk = 0; kk < 16; ++kk) {
      float ar[4], wr[4];
#pragma unroll
      for (int i = 0; i < 4; i++) ar[i] = As[kk][ty * 4 + i];
#pragma unroll
      for (int j = 0; j < 4; j++) wr[j] = Ws[kk][tx * 4 + j];
#pragma unroll
      for (int i = 0; i < 4; i++)
#pragma unroll
        for (int j = 0; j < 4; j++) acc[i][j] += ar[i] * wr[j];
    }
    __syncthreads();
  }
  float4 bv = make_float4(0.f, 0.f, 0.f, 0.f);
  if (bias) bv = *(const float4*)(bias + n0 + tx * 4);
#pragma unroll
  for (int i = 0; i < 4; i++) {
    float4 r;
    r.x = acc[i][0] + bv.x; r.y = acc[i][1] + bv.y;
    r.z = acc[i][2] + bv.z; r.w = acc[i][3] + bv.w;
    *(float4*)(C + (size_t)(m0 + ty * 4 + i) * N + n0 + tx * 4) = r;
  }
}

// ---------------------------------------------------------------- QK^T (batched over b,h)
__global__ __launch_bounds__(256) void k_gemm_qk(const float* __restrict__ qkv,
                                                 float* __restrict__ sc) {
  int bh = blockIdx.z, b = bh >> 3, hd = bh & 7;
  const float* Qb = qkv + (size_t)b * CS * CH3 + hd * CDH;
  const float* Kb = Qb + CH;
  __shared__ __align__(16) float As[16][64];
  __shared__ __align__(16) float Bs[16][64];
  int tid = threadIdx.x;
  int m0 = blockIdx.y * 64, n0 = blockIdx.x * 64;
  int lr = tid >> 2, lk = (tid & 3) << 2;
  int tx = tid & 15, ty = tid >> 4;
  float acc[4][4] = {};
  for (int k0 = 0; k0 < CDH; k0 += 16) {
    float4 a = *(const float4*)(Qb + (size_t)(m0 + lr) * CH3 + k0 + lk);
    float4 w = *(const float4*)(Kb + (size_t)(n0 + lr) * CH3 + k0 + lk);
    As[lk + 0][lr] = a.x; As[lk + 1][lr] = a.y; As[lk + 2][lr] = a.z; As[lk + 3][lr] = a.w;
    Bs[lk + 0][lr] = w.x; Bs[lk + 1][lr] = w.y; Bs[lk + 2][lr] = w.z; Bs[lk + 3][lr] = w.w;
    __syncthreads();
#pragma unroll
    for (int kk = 0; kk < 16; ++kk) {
      float ar[4], wr[4];
#pragma unroll
      for (int i = 0; i < 4; i++) ar[i] = As[kk][ty * 4 + i];
#pragma unroll
      for (int j = 0; j < 4; j++) wr[j] = Bs[kk][tx * 4 + j];
#pragma unroll
      for (int i = 0; i < 4; i++)
#pragma unroll
        for (int j = 0; j < 4; j++) acc[i][j] += ar[i] * wr[j];
    }
    __syncthreads();
  }
#pragma unroll
  for (int i = 0; i < 4; i++) {
    float4 r;
    r.x = acc[i][0] * 0.125f; r.y = acc[i][1] * 0.125f;
    r.z = acc[i][2] * 0.125f; r.w = acc[i][3] * 0.125f;
    *(float4*)(sc + ((size_t)bh * CS + m0 + ty * 4 + i) * CS + n0 + tx * 4) = r;
  }
}

// ---------------------------------------------------------------- softmax over rows of scores
__global__ __launch_bounds__(256) void k_softmax(float* __restrict__ sc) {
  size_t row = blockIdx.x;
  float* r = sc + row * CS;
  int tid = threadIdx.x;
  float v0 = r[tid], v1 = r[tid + 256];
  __shared__ float red[4];
  __shared__ float bval;
  int lane = tid & 63, wid = tid >> 6;
  float m = fmaxf(v0, v1);
#pragma unroll
  for (int o = 32; o; o >>= 1) m = fmaxf(m, __shfl_down(m, o, 64));
  if (!lane) red[wid] = m;
  __syncthreads();
  if (!tid) bval = fmaxf(fmaxf(red[0], red[1]), fmaxf(red[2], red[3]));
  __syncthreads();
  float mx = bval;
  float e0 = expf(v0 - mx), e1 = expf(v1 - mx);
  float s = e0 + e1;
#pragma unroll
  for (int o = 32; o; o >>= 1) s += __shfl_down(s, o, 64);
  __syncthreads();
  if (!lane) red[wid] = s;
  __syncthreads();
  if (!tid) bval = red[0] + red[1] + red[2] + red[3];
  __syncthreads();
  float sum = bval;
  r[tid] = e0 / sum;
  r[tid + 256] = e1 / sum;
}

// ---------------------------------------------------------------- P @ V (batched over b,h)
__global__ __launch_bounds__(256) void k_gemm_pv(const float* __restrict__ sc,
                                                 const float* __restrict__ qkv,
                                                 float* __restrict__ o) {
  int bh = blockIdx.z, b = bh >> 3, hd = bh & 7;
  const float* A = sc + (size_t)bh * CS * CS;
  const float* Vb = qkv + (size_t)b * CS * CH3 + 2 * CH + hd * CDH;
  __shared__ __align__(16) float As[16][64];
  __shared__ __align__(16) float Bs[16][64];
  int tid = threadIdx.x;
  int m0 = blockIdx.y * 64;
  int lr = tid >> 2, lk = (tid & 3) << 2;
  int jr = tid >> 4, dc = (tid & 15) << 2;
  int tx = tid & 15, ty = tid >> 4;
  float acc[4][4] = {};
  for (int k0 = 0; k0 < CS; k0 += 16) {
    float4 a = *(const float4*)(A + (size_t)(m0 + lr) * CS + k0 + lk);
    As[lk + 0][lr] = a.x; As[lk + 1][lr] = a.y; As[lk + 2][lr] = a.z; As[lk + 3][lr] = a.w;
    float4 v = *(const float4*)(Vb + (size_t)(k0 + jr) * CH3 + dc);
    *(float4*)&Bs[jr][dc] = v;
    __syncthreads();
#pragma unroll
    for (int kk = 0; kk < 16; ++kk) {
      float ar[4], br[4];
#pragma unroll
      for (int i = 0; i < 4; i++) ar[i] = As[kk][ty * 4 + i];
#pragma unroll
      for (int j = 0; j < 4; j++) br[j] = Bs[kk][tx * 4 + j];
#pragma unroll
      for (int i = 0; i < 4; i++)
#pragma unroll
        for (int j = 0; j < 4; j++) acc[i][j] += ar[i] * br[j];
    }
    __syncthreads();
  }
#pragma unroll
  for (int i = 0; i < 4; i++) {
    float4 r;
    r.x = acc[i][0]; r.y = acc[i][1]; r.z = acc[i][2]; r.w = acc[i][3];
    *(float4*)(o + ((size_t)b * CS + m0 + ty * 4 + i) * CH + hd * CDH + tx * 4) = r;
  }
}

// ---------------------------------------------------------------- x = LN(x + resid) * g + b
__global__ __launch_bounds__(256) void k_add_ln(const float* __restrict__ xin,
                                                const float* __restrict__ resid,
                                                const float* __restrict__ g,
                                                const float* __restrict__ b,
                                                float* __restrict__ xout) {
  int t = blockIdx.x, tid = threadIdx.x;
  float v0 = xin[(size_t)t * CH + tid];
  float v1 = xin[(size_t)t * CH + tid + 256];
  if (resid) {
    v0 += resid[(size_t)t * CH + tid];
    v1 += resid[(size_t)t * CH + tid + 256];
  }
  __shared__ float red[4];
  __shared__ float stat;
  int lane = tid & 63, wid = tid >> 6;
  float s = v0 + v1;
#pragma unroll
  for (int o = 32; o; o >>= 1) s += __shfl_down(s, o, 64);
  if (!lane) red[wid] = s;
  __syncthreads();
  if (!tid) stat = (red[0] + red[1] + red[2] + red[3]) * (1.f / CH);
  __syncthreads();
  float m = stat;
  float d0 = v0 - m, d1 = v1 - m;
  float q = d0 * d0 + d1 * d1;
#pragma unroll
  for (int o = 32; o; o >>= 1) q += __shfl_down(q, o, 64);
  __syncthreads();
  if (!lane) red[wid] = q;
  __syncthreads();
  if (!tid) stat = rsqrtf((red[0] + red[1] + red[2] + red[3]) * (1.f / CH) + 1e-5f);
  __syncthreads();
  float rs = stat;
  xout[(size_t)t * CH + tid] = d0 * rs * g[tid] + b[tid];
  xout[(size_t)t * CH + tid + 256] = d1 * rs * g[tid + 256] + b[tid + 256];
}

// ---------------------------------------------------------------- gate: softmax over E, top-1 route
__global__ __launch_bounds__(256) void k_gate(const float* __restrict__ xf,
                                              const float* __restrict__ gw,
                                              float* __restrict__ probs,
                                              float* __restrict__ gate,
                                              int* __restrict__ cnt,
                                              int* __restrict__ toklist) {
  int t = blockIdx.x, tid = threadIdx.x;
  float part[CE];
#pragma unroll
  for (int e = 0; e < CE; e++) part[e] = 0.f;
  for (int h = tid; h < CH; h += 256) {
    float xv = xf[(size_t)t * CH + h];
#pragma unroll
    for (int e = 0; e < CE; e++) part[e] += xv * gw[e * CH + h];
  }
  __shared__ float red[CE][4];
  int lane = tid & 63, wid = tid >> 6;
#pragma unroll
  for (int e = 0; e < CE; e++) {
    float v = part[e];
#pragma unroll
    for (int o = 32; o; o >>= 1) v += __shfl_down(v, o, 64);
    if (!lane) red[e][wid] = v;
  }
  __syncthreads();
  if (tid == 0) {
    float lg[CE], mx = -1e30f;
#pragma unroll
    for (int e = 0; e < CE; e++) {
      lg[e] = red[e][0] + red[e][1] + red[e][2] + red[e][3];
      mx = fmaxf(mx, lg[e]);
    }
    float p[CE], sum = 0.f;
#pragma unroll
    for (int e = 0; e < CE; e++) { p[e] = expf(lg[e] - mx); sum += p[e]; }
    float best = -1.f; int bi = 0;
#pragma unroll
    for (int e = 0; e < CE; e++) {
      p[e] /= sum;
      probs[(size_t)t * CE + e] = p[e];
      if (p[e] > best) { best = p[e]; bi = e; }
    }
    gate[t] = best / (best + 1e-8f);
    int pos = atomicAdd(&cnt[bi], 1);
    toklist[bi * CT + pos] = t;
  }
}

// ---------------------------------------------------------------- MoE GEMM1: hid = relu(xf @ W1[e]^T + b1[e]) for routed tokens
__global__ __launch_bounds__(256) void k_moe1(const float* __restrict__ xf,
                                              const float* __restrict__ w1,
                                              const float* __restrict__ b1,
                                              const int* __restrict__ cnt,
                                              const int* __restrict__ toklist,
                                              float* __restrict__ hid, int l) {
  int e = blockIdx.z;
  int n = cnt[e];
  int r0 = blockIdx.y * 64;
  if (r0 >= n) return;
  __shared__ int toks[64];
  int tid = threadIdx.x;
  if (tid < 64) toks[tid] = (r0 + tid < n) ? toklist[e * CT + r0 + tid] : -1;
  __syncthreads();
  const float* W = w1 + (size_t)(l * CE + e) * CFF * CH;
  const float* bb = b1 + (size_t)(l * CE + e) * CFF;
  int f0 = blockIdx.x * 64;
  __shared__ __align__(16) float As[16][64];
  __shared__ __align__(16) float Ws[16][64];
  int lr = tid >> 2, lk = (tid & 3) << 2;
  int tx = tid & 15, ty = tid >> 4;
  int tokA = toks[lr];
  float acc[4][4] = {};
  for (int k0 = 0; k0 < CH; k0 += 16) {
    float4 a = make_float4(0.f, 0.f, 0.f, 0.f);
    if (tokA >= 0) a = *(const float4*)(xf + (size_t)tokA * CH + k0 + lk);
    float4 w = *(const float4*)(W + (size_t)(f0 + lr) * CH + k0 + lk);
    As[lk + 0][lr] = a.x; As[lk + 1][lr] = a.y; As[lk + 2][lr] = a.z; As[lk + 3][lr] = a.w;
    Ws[lk + 0][lr] = w.x; Ws[lk + 1][lr] = w.y; Ws[lk + 2][lr] = w.z; Ws[lk + 3][lr] = w.w;
    __syncthreads();
#pragma unroll
    for (int kk = 0; kk < 16; ++kk) {
      float ar[4], wr[4];
#pragma unroll
      for (int i = 0; i < 4; i++) ar[i] = As[kk][ty * 4 + i];
#pragma unroll
      for (int j = 0; j < 4; j++) wr[j] = Ws[kk][tx * 4 + j];
#pragma unroll
      for (int i = 0; i < 4; i++)
#pragma unroll
        for (int j = 0; j < 4; j++) acc[i][j] += ar[i] * wr[j];
    }
    __syncthreads();
  }
  float4 bv = *(const float4*)(bb + f0 + tx * 4);
#pragma unroll
  for (int i = 0; i < 4; i++) {
    int tok = toks[ty * 4 + i];
    if (tok < 0) continue;
    float4 r;
    r.x = fmaxf(acc[i][0] + bv.x, 0.f);
    r.y = fmaxf(acc[i][1] + bv.y, 0.f);
    r.z = fmaxf(acc[i][2] + bv.z, 0.f);
    r.w = fmaxf(acc[i][3] + bv.w, 0.f);
    *(float4*)(hid + (size_t)tok * CFF + f0 + tx * 4) = r;
  }
}

// ---------------------------------------------------------------- MoE GEMM2: moe = gate * (hid @ W2[e]^T + b2[e])
__global__ __launch_bounds__(256) void k_moe2(const float* __restrict__ hid,
                                              const float* __restrict__ w2,
                                              const float* __restrict__ b2,
                                              const int* __restrict__ cnt,
                                              const int* __restrict__ toklist,
                                              const float* __restrict__ gate,
                                              float* __restrict__ moe, int l) {
  int e = blockIdx.z;
  int n = cnt[e];
  int r0 = blockIdx.y * 64;
  if (r0 >= n) return;
  __shared__ int toks[64];
  int tid = threadIdx.x;
  if (tid < 64) toks[tid] = (r0 + tid < n) ? toklist[e * CT + r0 + tid] : -1;
  __syncthreads();
  const float* W = w2 + (size_t)(l * CE + e) * CH * CFF;
  const float* bb = b2 + (size_t)(l * CE + e) * CH;
  int h0 = blockIdx.x * 64;
  __shared__ __align__(16) float As[16][64];
  __shared__ __align__(16) float Ws[16][64];
  int lr = tid >> 2, lk = (tid & 3) << 2;
  int tx = tid & 15, ty = tid >> 4;
  int tokA = toks[lr];
  float acc[4][4] = {};
  for (int k0 = 0; k0 < CFF; k0 += 16) {
    float4 a = make_float4(0.f, 0.f, 0.f, 0.f);
    if (tokA >= 0) a = *(const float4*)(hid + (size_t)tokA * CFF + k0 + lk);
    float4 w = *(const float4*)(W + (size_t)(h0 + lr) * CFF + k0 + lk);
    As[lk + 0][lr] = a.x; As[lk + 1][lr] = a.y; As[lk + 2][lr] = a.z; As[lk + 3][lr] = a.w;
    Ws[lk + 0][lr] = w.x; Ws[lk + 1][lr] = w.y; Ws[lk + 2][lr] = w.z; Ws[lk + 3][lr] = w.w;
    __syncthreads();
#pragma unroll
    for (int kk = 0; kk < 16; ++kk) {
      float ar[4], wr[4];
#pragma unroll
      for (int i = 0; i < 4; i++) ar[i] = As[kk][ty * 4 + i];
#pragma unroll
      for (int j = 0; j < 4; j++) wr[j] = Ws[kk][tx * 4 + j];
#pragma unroll
      for (int i = 0; i < 4; i++)
#pragma unroll
        for (int j = 0; j < 4; j++) acc[i][j] += ar[i] * wr[j];
    }
    __syncthreads();
  }
  float4 bv = *(const float4*)(bb + h0 + tx * 4);
#pragma unroll
  for (int i = 0; i < 4; i++) {
    int tok = toks[ty * 4 + i];
    if (tok < 0) continue;
    float gv = gate[tok];
    float4 r;
    r.x = gv * (acc[i][0] + bv.x);
    r.y = gv * (acc[i][1] + bv.y);
    r.z = gv * (acc[i][2] + bv.z);
    r.w = gv * (acc[i][3] + bv.w);
    *(float4*)(moe + (size_t)tok * CH + h0 + tx * 4) = r;
  }
}

// ---------------------------------------------------------------- load-balance loss for one layer; clears cnt for next layer
__global__ __launch_bounds__(256) void k_lb(const float* __restrict__ probs,
                                            int* __restrict__ cnt,
                                            float* __restrict__ lbacc) {
  int tid = threadIdx.x;
  float part[CE];
#pragma unroll
  for (int e = 0; e < CE; e++) part[e] = 0.f;
  for (int t = tid; t < CT; t += 256) {
#pragma unroll
    for (int e = 0; e < CE; e++) part[e] += probs[(size_t)t * CE + e];
  }
  __shared__ float red[CE][4];
  int lane = tid & 63, wid = tid >> 6;
#pragma unroll
  for (int e = 0; e < CE; e++) {
    float v = part[e];
#pragma unroll
    for (int o = 32; o; o >>= 1) v += __shfl_down(v, o, 64);
    if (!lane) red[e][wid] = v;
  }
  __syncthreads();
  if (tid == 0) {
    float lb = 0.f;
#pragma unroll
    for (int e = 0; e < CE; e++) {
      float rp = (red[e][0] + red[e][1] + red[e][2] + red[e][3]) / (float)CT;
      float eu = (float)cnt[e] / (float)CT;
      lb += rp * eu;
    }
    lbacc[0] += (float)CE * lb;
  }
  __syncthreads();
  if (tid < CE) cnt[tid] = 0;
}

// ---------------------------------------------------------------- final scalar output
__global__ void k_write_lb(const float* __restrict__ lbacc, float* __restrict__ out) {
  out[(size_t)CT * CV] = lbacc[0] / (float)CL;
}

// ================================================================ launcher
extern "C" void kernel_launch(void* const* d_in, const int* in_sizes, int n_in,
                              void* d_out, int out_size, void* d_ws, size_t ws_size,
                              hipStream_t stream) {
  const int* ids = (const int*)d_in[0];
  const float* emb = (const float*)d_in[1];
  const float* pos = (const float*)d_in[2];
  const float* aiw = (const float*)d_in[3];
  const float* aib = (const float*)d_in[4];
  const float* aow = (const float*)d_in[5];
  const float* aob = (const float*)d_in[6];
  const float* l1g = (const float*)d_in[7];
  const float* l1b = (const float*)d_in[8];
  const float* gw = (const float*)d_in[9];
  const float* w1 = (const float*)d_in[10];
  const float* b1 = (const float*)d_in[11];
  const float* w2 = (const float*)d_in[12];
  const float* b2 = (const float*)d_in[13];
  const float* l2g = (const float*)d_in[14];
  const float* l2b = (const float*)d_in[15];
  const float* lnfg = (const float*)d_in[16];
  const float* lnfb = (const float*)d_in[17];
  const float* lmw = (const float*)d_in[18];
  float* out = (float*)d_out;

  float* ws = (float*)d_ws;
  size_t off = 0;
  float* x = ws + off;      off += (size_t)CT * CH;
  float* qkv = ws + off;    off += (size_t)CT * CH3;
  float* sc = ws + off;     off += (size_t)CB * CNH * CS * CS;
  float* attno = ws + off;  off += (size_t)CT * CH;
  float* hid = ws + off;    off += (size_t)CT * CFF;
  float* moe = ws + off;    off += (size_t)CT * CH;
  float* probs = ws + off;  off += (size_t)CT * CE;
  float* gate = ws + off;   off += (size_t)CT;
  float* lbacc = ws + off;  off += 1;
  int* cnt = (int*)(ws + off);
  int* toklist = cnt + CE;

  dim3 blk(256);
  k_init<<<1, 64, 0, stream>>>(cnt, lbacc);
  k_embed<<<(CT * CH / 4) / 256, blk, 0, stream>>>(ids, emb, pos, x);
  for (int l = 0; l < CL; l++) {
    // QKV projection
    k_gemm_bt<<<dim3(CH3 / 64, CT / 64), blk, 0, stream>>>(
        x, aiw + (size_t)l * CH3 * CH, aib + (size_t)l * CH3, qkv, CH3, CH);
    // attention
    k_gemm_qk<<<dim3(CS / 64, CS / 64, CB * CNH), blk, 0, stream>>>(qkv, sc);
    k_softmax<<<CB * CNH * CS, blk, 0, stream>>>(sc);
    k_gemm_pv<<<dim3(1, CS / 64, CB * CNH), blk, 0, stream>>>(sc, qkv, attno);
    // output projection -> moe buffer (used as temp)
    k_gemm_bt<<<dim3(CH / 64, CT / 64), blk, 0, stream>>>(
        attno, aow + (size_t)l * CH * CH, aob + (size_t)l * CH, moe, CH, CH);
    k_add_ln<<<CT, blk, 0, stream>>>(x, moe, l1g + (size_t)l * CH, l1b + (size_t)l * CH, x);
    // MoE: route, grouped expert GEMMs (top-1 only)
    k_gate<<<CT, blk, 0, stream>>>(x, gw + (size_t)l * CE * CH, probs, gate, cnt, toklist);
    k_moe1<<<dim3(CFF / 64, CT / 64, CE), blk, 0, stream>>>(x, w1, b1, cnt, toklist, hid, l);
    k_moe2<<<dim3(CH / 64, CT / 64, CE), blk, 0, stream>>>(hid, w2, b2, cnt, toklist, gate, moe, l);
    k_add_ln<<<CT, blk, 0, stream>>>(x, moe, l2g + (size_t)l * CH, l2b + (size_t)l * CH, x);
    k_lb<<<1, blk, 0, stream>>>(probs, cnt, lbacc);
  }
  // final LN + LM head
  k_add_ln<<<CT, blk, 0, stream>>>(x, nullptr, lnfg, lnfb, attno);
  k_gemm_bt<<<dim3(CV / 64, CT / 64), blk, 0, stream>>>(attno, lmw, nullptr, out, CV, CH);
  k_write_lb<<<1, 1, 0, stream>>>(lbacc, out);
}

// Round 4
// 7190.063 us; speedup vs baseline: 1.0368x; 1.0368x over previous
//
#include <hip/hip_runtime.h>
#include <math.h>

// SmallSwitchTransformer forward. Hybrid precision:
//  - fp32 (improved 128x128/8x8 vector GEMM) for everything that feeds MoE
//    routing decisions (attention, qkv, attn-out, MoE layers 0-4).
//  - bf16 MFMA (16x16x32) for routing-safe GEMMs: LM head + layer-5 MoE.
// MoE computes only the routed top-1 expert (identical math to the dense
// reference which masks with one-hot).

typedef unsigned short u16;
typedef __attribute__((ext_vector_type(8))) short s8v;
typedef __attribute__((ext_vector_type(4))) float f4v;

constexpr int CB = 8, CS = 512, CH = 512, CNH = 8, CDH = 64, CE = 8;
constexpr int CFF = 2048, CL = 6, CV = 32000;
constexpr int CT = CB * CS, CH3 = 3 * CH;

__device__ __forceinline__ u16 f2b(float f) {
  unsigned u = __builtin_bit_cast(unsigned, f);
  return (u16)((u + 0x7fffu + ((u >> 16) & 1u)) >> 16);
}
__device__ __forceinline__ float b2f(u16 h) {
  unsigned u = ((unsigned)h) << 16;
  return __builtin_bit_cast(float, u);
}

// ---------------------------------------------------------------- init
__global__ __launch_bounds__(64) void k_init(int* cnt, float* lbacc) {
  int tid = threadIdx.x;
  if (tid < CE) cnt[tid] = 0;
  if (tid == 0) *lbacc = 0.f;
}

// ---------------------------------------------------------------- embedding (writes fp32 + bf16 copies)
__global__ __launch_bounds__(256) void k_embed(const int* __restrict__ ids,
                                               const float* __restrict__ emb,
                                               const float* __restrict__ pos,
                                               float* __restrict__ x,
                                               u16* __restrict__ xbf) {
  int i = blockIdx.x * 256 + threadIdx.x;
  int t = i / (CH / 4);
  int h4 = i % (CH / 4);
  int id = ids[t];
  float4 e = ((const float4*)(emb + (size_t)id * CH))[h4];
  float4 p = ((const float4*)(pos + (size_t)(t % CS) * CH))[h4];
  float4 r;
  r.x = e.x + p.x; r.y = e.y + p.y; r.z = e.z + p.z; r.w = e.w + p.w;
  ((float4*)(x + (size_t)t * CH))[h4] = r;
  unsigned long long pk = (unsigned long long)f2b(r.x) |
                          ((unsigned long long)f2b(r.y) << 16) |
                          ((unsigned long long)f2b(r.z) << 32) |
                          ((unsigned long long)f2b(r.w) << 48);
  *(unsigned long long*)(xbf + (size_t)t * CH + h4 * 4) = pk;
}

// ================================================================ fp32 GEMM core
// C[M,N] = A[M,K] @ W[N,K]^T (+bias).  128x128 tile, 8x8 microtile/thread.
// EP: 0 = plain(+bias), 1 = scale (no bias), 3 = gather+bias+relu, 4 = gather+bias+gate
template <bool GATHER, int EP>
__device__ __forceinline__ void mm32_core(
    const float* __restrict__ A, int lda, const float* __restrict__ W, int ldw,
    int K, const float* __restrict__ bias, float scale,
    float* __restrict__ C, int ldc, int m0, int n0,
    const int* __restrict__ tokl, int nrows, const float* __restrict__ gatev) {
  __shared__ __align__(16) float As[16][128];
  __shared__ __align__(16) float Ws[16][128];
  __shared__ int toks[128];
  const int tid = threadIdx.x;
  if (GATHER) {
    if (tid < 128) toks[tid] = (tid < nrows) ? tokl[tid] : -1;
    __syncthreads();
  }
  const int lr = tid >> 1, half = tid & 1;
  const float* gA;
  if (GATHER) {
    int t = toks[lr]; if (t < 0) t = 0;
    gA = A + (size_t)t * lda + half * 8;
  } else {
    gA = A + (size_t)(m0 + lr) * lda + half * 8;
  }
  const float* gW = W + (size_t)(n0 + lr) * ldw + half * 8;
  const int tx = tid & 15, ty = tid >> 4;
  float acc[8][8];
#pragma unroll
  for (int i = 0; i < 8; i++)
#pragma unroll
    for (int j = 0; j < 8; j++) acc[i][j] = 0.f;

  for (int k0 = 0; k0 < K; k0 += 16) {
    float4 a0 = *(const float4*)(gA + k0);
    float4 a1 = *(const float4*)(gA + k0 + 4);
    float4 w0 = *(const float4*)(gW + k0);
    float4 w1 = *(const float4*)(gW + k0 + 4);
    __syncthreads();
    int kb = half * 8;
    As[kb + 0][lr] = a0.x; As[kb + 1][lr] = a0.y; As[kb + 2][lr] = a0.z; As[kb + 3][lr] = a0.w;
    As[kb + 4][lr] = a1.x; As[kb + 5][lr] = a1.y; As[kb + 6][lr] = a1.z; As[kb + 7][lr] = a1.w;
    Ws[kb + 0][lr] = w0.x; Ws[kb + 1][lr] = w0.y; Ws[kb + 2][lr] = w0.z; Ws[kb + 3][lr] = w0.w;
    Ws[kb + 4][lr] = w1.x; Ws[kb + 5][lr] = w1.y; Ws[kb + 6][lr] = w1.z; Ws[kb + 7][lr] = w1.w;
    __syncthreads();
#pragma unroll
    for (int kk = 0; kk < 16; ++kk) {
      float ar[8], br[8];
      *(float4*)(ar + 0) = *(const float4*)&As[kk][ty * 4];
      *(float4*)(ar + 4) = *(const float4*)&As[kk][64 + ty * 4];
      *(float4*)(br + 0) = *(const float4*)&Ws[kk][tx * 4];
      *(float4*)(br + 4) = *(const float4*)&Ws[kk][64 + tx * 4];
#pragma unroll
      for (int i = 0; i < 8; i++)
#pragma unroll
        for (int j = 0; j < 8; j++) acc[i][j] = fmaf(ar[i], br[j], acc[i][j]);
    }
  }
  // epilogue: rows gi*64+ty*4+i, cols gj*64+tx*4+j
#pragma unroll
  for (int gj = 0; gj < 2; gj++) {
    int cloc = gj * 64 + tx * 4;
    float4 bv = make_float4(0.f, 0.f, 0.f, 0.f);
    if (EP != 1 && bias) bv = *(const float4*)(bias + n0 + cloc);
#pragma unroll
    for (int gi = 0; gi < 2; gi++) {
#pragma unroll
      for (int i = 0; i < 4; i++) {
        int rloc = gi * 64 + ty * 4 + i;
        float4 v;
        v.x = acc[gi * 4 + i][gj * 4 + 0];
        v.y = acc[gi * 4 + i][gj * 4 + 1];
        v.z = acc[gi * 4 + i][gj * 4 + 2];
        v.w = acc[gi * 4 + i][gj * 4 + 3];
        if (EP == 0) {
          v.x += bv.x; v.y += bv.y; v.z += bv.z; v.w += bv.w;
          *(float4*)(C + (size_t)(m0 + rloc) * ldc + n0 + cloc) = v;
        } else if (EP == 1) {
          v.x *= scale; v.y *= scale; v.z *= scale; v.w *= scale;
          *(float4*)(C + (size_t)(m0 + rloc) * ldc + n0 + cloc) = v;
        } else if (EP == 3) {
          int tok = toks[rloc];
          if (tok >= 0) {
            v.x = fmaxf(v.x + bv.x, 0.f); v.y = fmaxf(v.y + bv.y, 0.f);
            v.z = fmaxf(v.z + bv.z, 0.f); v.w = fmaxf(v.w + bv.w, 0.f);
            *(float4*)(C + (size_t)tok * ldc + n0 + cloc) = v;
          }
        } else {
          int tok = toks[rloc];
          if (tok >= 0) {
            float gv = gatev[tok];
            v.x = (v.x + bv.x) * gv; v.y = (v.y + bv.y) * gv;
            v.z = (v.z + bv.z) * gv; v.w = (v.w + bv.w) * gv;
            *(float4*)(C + (size_t)tok * ldc + n0 + cloc) = v;
          }
        }
      }
    }
  }
}

__global__ __launch_bounds__(256) void k_lin32(const float* A, int lda, const float* W, int ldw,
                                               int K, const float* bias, float* C, int ldc) {
  mm32_core<false, 0>(A, lda, W, ldw, K, bias, 1.f, C, ldc,
                      blockIdx.y * 128, blockIdx.x * 128, nullptr, 0, nullptr);
}
__global__ __launch_bounds__(256) void k_qk32(const float* qkv, float* sc) {
  int z = blockIdx.z;
  const float* A = qkv + (size_t)(z >> 3) * CS * CH3 + (z & 7) * CDH;
  mm32_core<false, 1>(A, CH3, A + CH, CH3, CDH, nullptr, 0.125f,
                      sc + (size_t)z * CS * CS, CS,
                      blockIdx.y * 128, blockIdx.x * 128, nullptr, 0, nullptr);
}
__global__ __launch_bounds__(256) void k_moe1_32(const float* x, const float* w1, const float* b1,
                                                 const int* cnt, const int* tokl, float* hid) {
  int e = blockIdx.z, n = cnt[e], r0 = blockIdx.y * 128;
  if (r0 >= n) return;
  mm32_core<true, 3>(x, CH, w1 + (size_t)e * CFF * CH, CH, CH, b1 + e * CFF, 1.f,
                     hid, CFF, 0, blockIdx.x * 128, tokl + e * CT + r0, n - r0, nullptr);
}
__global__ __launch_bounds__(256) void k_moe2_32(const float* hid, const float* w2, const float* b2,
                                                 const int* cnt, const int* tokl,
                                                 const float* gate, float* outp) {
  int e = blockIdx.z, n = cnt[e], r0 = blockIdx.y * 128;
  if (r0 >= n) return;
  mm32_core<true, 4>(hid, CFF, w2 + (size_t)e * CH * CFF, CFF, CFF, b2 + e * CH, 1.f,
                     outp, CH, 0, blockIdx.x * 128, tokl + e * CT + r0, n - r0, gate);
}

// ================================================================ bf16 MFMA GEMM core
// C = A @ W^T (+bias). 128x128 tile, 4 waves (2x2), 16x16x32 MFMA.
// LDS pitch 40 bf16 (80B) for uniform bank distribution.
// EP: 0 = fp32 out (+bias), 3 = gather+relu -> bf16 out, 4 = gather+gate -> fp32 out
template <bool GATHER, int EP>
__device__ __forceinline__ void mmbf_core(
    const u16* __restrict__ A, int lda, const u16* __restrict__ W, int ldw,
    int K, const float* __restrict__ bias,
    float* __restrict__ Cf, u16* __restrict__ Cb, int ldc, int m0, int n0,
    const int* __restrict__ tokl, int nrows, const float* __restrict__ gatev) {
  __shared__ __align__(16) u16 As[128 * 40];
  __shared__ __align__(16) u16 Ws[128 * 40];
  __shared__ int toks[128];
  const int tid = threadIdx.x, lane = tid & 63, w = tid >> 6;
  const int wr = w >> 1, wc = w & 1, r = lane & 15, g = lane >> 4;
  if (GATHER) {
    if (tid < 128) toks[tid] = (tid < nrows) ? tokl[tid] : -1;
    __syncthreads();
  }
  const int sr = tid >> 1, sh = (tid & 1) * 16;
  const u16* gA;
  if (GATHER) {
    int t = toks[sr]; if (t < 0) t = 0;
    gA = A + (size_t)t * lda + sh;
  } else {
    gA = A + (size_t)(m0 + sr) * lda + sh;
  }
  const u16* gW = W + (size_t)(n0 + sr) * ldw + sh;
  u16* lA = As + sr * 40 + sh;
  u16* lW = Ws + sr * 40 + sh;
  f4v acc[4][4];
#pragma unroll
  for (int m = 0; m < 4; m++)
#pragma unroll
    for (int n = 0; n < 4; n++) { f4v z = {0.f, 0.f, 0.f, 0.f}; acc[m][n] = z; }

  for (int k0 = 0; k0 < K; k0 += 32) {
    s8v a0 = *(const s8v*)(gA + k0);
    s8v a1 = *(const s8v*)(gA + k0 + 8);
    s8v w0 = *(const s8v*)(gW + k0);
    s8v w1 = *(const s8v*)(gW + k0 + 8);
    __syncthreads();
    *(s8v*)lA = a0; *(s8v*)(lA + 8) = a1;
    *(s8v*)lW = w0; *(s8v*)(lW + 8) = w1;
    __syncthreads();
    s8v av[4], bv[4];
#pragma unroll
    for (int m = 0; m < 4; m++)
      av[m] = *(const s8v*)(As + (wr * 64 + m * 16 + r) * 40 + g * 8);
#pragma unroll
    for (int n = 0; n < 4; n++)
      bv[n] = *(const s8v*)(Ws + (wc * 64 + n * 16 + r) * 40 + g * 8);
#pragma unroll
    for (int m = 0; m < 4; m++)
#pragma unroll
      for (int n = 0; n < 4; n++)
        acc[m][n] = __builtin_amdgcn_mfma_f32_16x16x32_bf16(av[m], bv[n], acc[m][n], 0, 0, 0);
  }
  // epilogue: C/D frag: col = lane&15, row = (lane>>4)*4 + j  [m89/m91 verified]
  const int cb = n0 + wc * 64;
#pragma unroll
  for (int m = 0; m < 4; m++) {
    int wrow = wr * 64 + m * 16 + (lane >> 4) * 4;
#pragma unroll
    for (int n = 0; n < 4; n++) {
      int col = cb + n * 16 + r;
      float bv_ = bias ? bias[col] : 0.f;
      if (EP == 0) {
#pragma unroll
        for (int j = 0; j < 4; j++)
          Cf[(size_t)(m0 + wrow + j) * ldc + col] = acc[m][n][j] + bv_;
      } else if (EP == 3) {
#pragma unroll
        for (int j = 0; j < 4; j++) {
          int tok = toks[wrow + j];
          if (tok < 0) continue;
          Cb[(size_t)tok * ldc + col] = f2b(fmaxf(acc[m][n][j] + bv_, 0.f));
        }
      } else {
#pragma unroll
        for (int j = 0; j < 4; j++) {
          int tok = toks[wrow + j];
          if (tok < 0) continue;
          Cf[(size_t)tok * ldc + col] = (acc[m][n][j] + bv_) * gatev[tok];
        }
      }
    }
  }
}

__global__ __launch_bounds__(256) void k_linbf(const u16* A, int lda, const u16* W, int ldw,
                                               int K, const float* bias, float* C, int ldc) {
  mmbf_core<false, 0>(A, lda, W, ldw, K, bias, C, nullptr, ldc,
                      blockIdx.y * 128, blockIdx.x * 128, nullptr, 0, nullptr);
}
__global__ __launch_bounds__(256) void k_moe1_bf(const u16* xbf, const u16* w1b, const float* b1,
                                                 const int* cnt, const int* tokl, u16* hidb) {
  int e = blockIdx.z, n = cnt[e], r0 = blockIdx.y * 128;
  if (r0 >= n) return;
  mmbf_core<true, 3>(xbf, CH, w1b + (size_t)e * CFF * CH, CH, CH, b1 + e * CFF,
                     nullptr, hidb, CFF, 0, blockIdx.x * 128, tokl + e * CT + r0, n - r0, nullptr);
}
__global__ __launch_bounds__(256) void k_moe2_bf(const u16* hidb, const u16* w2b, const float* b2,
                                                 const int* cnt, const int* tokl,
                                                 const float* gate, float* outp) {
  int e = blockIdx.z, n = cnt[e], r0 = blockIdx.y * 128;
  if (r0 >= n) return;
  mmbf_core<true, 4>(hidb, CFF, w2b + (size_t)e * CH * CFF, CFF, CFF, b2 + e * CH,
                     outp, nullptr, CH, 0, blockIdx.x * 128, tokl + e * CT + r0, n - r0, gate);
}

// ---------------------------------------------------------------- fp32 -> bf16 conversion
__global__ __launch_bounds__(256) void k_f2b(const float* __restrict__ s, u16* __restrict__ d, int n4) {
  int i = blockIdx.x * 256 + threadIdx.x;
  if (i >= n4) return;
  float4 v = ((const float4*)s)[i];
  unsigned long long pk = (unsigned long long)f2b(v.x) |
                          ((unsigned long long)f2b(v.y) << 16) |
                          ((unsigned long long)f2b(v.z) << 32) |
                          ((unsigned long long)f2b(v.w) << 48);
  *(unsigned long long*)(d + (size_t)i * 4) = pk;
}

// ---------------------------------------------------------------- softmax over rows of scores (fp32)
__global__ __launch_bounds__(256) void k_softmax(float* __restrict__ sc) {
  size_t row = blockIdx.x;
  float* r = sc + row * CS;
  int tid = threadIdx.x;
  float v0 = r[tid], v1 = r[tid + 256];
  __shared__ float red[4];
  __shared__ float bval;
  int lane = tid & 63, wid = tid >> 6;
  float m = fmaxf(v0, v1);
#pragma unroll
  for (int o = 32; o; o >>= 1) m = fmaxf(m, __shfl_down(m, o, 64));
  if (!lane) red[wid] = m;
  __syncthreads();
  if (!tid) bval = fmaxf(fmaxf(red[0], red[1]), fmaxf(red[2], red[3]));
  __syncthreads();
  float mx = bval;
  float e0 = expf(v0 - mx), e1 = expf(v1 - mx);
  float s = e0 + e1;
#pragma unroll
  for (int o = 32; o; o >>= 1) s += __shfl_down(s, o, 64);
  __syncthreads();
  if (!lane) red[wid] = s;
  __syncthreads();
  if (!tid) bval = red[0] + red[1] + red[2] + red[3];
  __syncthreads();
  float sum = bval;
  r[tid] = e0 / sum;
  r[tid + 256] = e1 / sum;
}

// ---------------------------------------------------------------- P @ V (fp32, 64x64 tiles)
__global__ __launch_bounds__(256) void k_gemm_pv(const float* __restrict__ sc,
                                                 const float* __restrict__ qkv,
                                                 float* __restrict__ o) {
  int bh = blockIdx.z, b = bh >> 3, hd = bh & 7;
  const float* A = sc + (size_t)bh * CS * CS;
  const float* Vb = qkv + (size_t)b * CS * CH3 + 2 * CH + hd * CDH;
  __shared__ __align__(16) float As[16][64];
  __shared__ __align__(16) float Bs[16][64];
  int tid = threadIdx.x;
  int m0 = blockIdx.y * 64;
  int lr = tid >> 2, lk = (tid & 3) << 2;
  int jr = tid >> 4, dc = (tid & 15) << 2;
  int tx = tid & 15, ty = tid >> 4;
  float acc[4][4] = {};
  for (int k0 = 0; k0 < CS; k0 += 16) {
    float4 a = *(const float4*)(A + (size_t)(m0 + lr) * CS + k0 + lk);
    As[lk + 0][lr] = a.x; As[lk + 1][lr] = a.y; As[lk + 2][lr] = a.z; As[lk + 3][lr] = a.w;
    float4 v = *(const float4*)(Vb + (size_t)(k0 + jr) * CH3 + dc);
    *(float4*)&Bs[jr][dc] = v;
    __syncthreads();
#pragma unroll
    for (int kk = 0; kk < 16; ++kk) {
      float ar[4], br[4];
#pragma unroll
      for (int i = 0; i < 4; i++) ar[i] = As[kk][ty * 4 + i];
#pragma unroll
      for (int j = 0; j < 4; j++) br[j] = Bs[kk][tx * 4 + j];
#pragma unroll
      for (int i = 0; i < 4; i++)
#pragma unroll
        for (int j = 0; j < 4; j++) acc[i][j] = fmaf(ar[i], br[j], acc[i][j]);
    }
    __syncthreads();
  }
#pragma unroll
  for (int i = 0; i < 4; i++) {
    float4 r;
    r.x = acc[i][0]; r.y = acc[i][1]; r.z = acc[i][2]; r.w = acc[i][3];
    *(float4*)(o + ((size_t)b * CS + m0 + ty * 4 + i) * CH + hd * CDH + tx * 4) = r;
  }
}

// ---------------------------------------------------------------- x = LN(x + resid); writes fp32 + bf16
__global__ __launch_bounds__(256) void k_add_ln(const float* __restrict__ xin,
                                                const float* __restrict__ resid,
                                                const float* __restrict__ g,
                                                const float* __restrict__ b,
                                                float* __restrict__ xout,
                                                u16* __restrict__ xbf) {
  int t = blockIdx.x, tid = threadIdx.x;
  float v0 = xin[(size_t)t * CH + tid];
  float v1 = xin[(size_t)t * CH + tid + 256];
  if (resid) {
    v0 += resid[(size_t)t * CH + tid];
    v1 += resid[(size_t)t * CH + tid + 256];
  }
  __shared__ float red[4];
  __shared__ float stat;
  int lane = tid & 63, wid = tid >> 6;
  float s = v0 + v1;
#pragma unroll
  for (int o = 32; o; o >>= 1) s += __shfl_down(s, o, 64);
  if (!lane) red[wid] = s;
  __syncthreads();
  if (!tid) stat = (red[0] + red[1] + red[2] + red[3]) * (1.f / CH);
  __syncthreads();
  float m = stat;
  float d0 = v0 - m, d1 = v1 - m;
  float q = d0 * d0 + d1 * d1;
#pragma unroll
  for (int o = 32; o; o >>= 1) q += __shfl_down(q, o, 64);
  __syncthreads();
  if (!lane) red[wid] = q;
  __syncthreads();
  if (!tid) stat = rsqrtf((red[0] + red[1] + red[2] + red[3]) * (1.f / CH) + 1e-5f);
  __syncthreads();
  float rs = stat;
  float o0 = d0 * rs * g[tid] + b[tid];
  float o1 = d1 * rs * g[tid + 256] + b[tid + 256];
  xout[(size_t)t * CH + tid] = o0;
  xout[(size_t)t * CH + tid + 256] = o1;
  xbf[(size_t)t * CH + tid] = f2b(o0);
  xbf[(size_t)t * CH + tid + 256] = f2b(o1);
}

// ---------------------------------------------------------------- gate: softmax over E, top-1 route
__global__ __launch_bounds__(256) void k_gate(const float* __restrict__ xf,
                                              const float* __restrict__ gw,
                                              float* __restrict__ probs,
                                              float* __restrict__ gate,
                                              int* __restrict__ cnt,
                                              int* __restrict__ toklist) {
  int t = blockIdx.x, tid = threadIdx.x;
  float part[CE];
#pragma unroll
  for (int e = 0; e < CE; e++) part[e] = 0.f;
  for (int h = tid; h < CH; h += 256) {
    float xv = xf[(size_t)t * CH + h];
#pragma unroll
    for (int e = 0; e < CE; e++) part[e] += xv * gw[e * CH + h];
  }
  __shared__ float red[CE][4];
  int lane = tid & 63, wid = tid >> 6;
#pragma unroll
  for (int e = 0; e < CE; e++) {
    float v = part[e];
#pragma unroll
    for (int o = 32; o; o >>= 1) v += __shfl_down(v, o, 64);
    if (!lane) red[e][wid] = v;
  }
  __syncthreads();
  if (tid == 0) {
    float lg[CE], mx = -1e30f;
#pragma unroll
    for (int e = 0; e < CE; e++) {
      lg[e] = red[e][0] + red[e][1] + red[e][2] + red[e][3];
      mx = fmaxf(mx, lg[e]);
    }
    float p[CE], sum = 0.f;
#pragma unroll
    for (int e = 0; e < CE; e++) { p[e] = expf(lg[e] - mx); sum += p[e]; }
    float best = -1.f; int bi = 0;
#pragma unroll
    for (int e = 0; e < CE; e++) {
      p[e] /= sum;
      probs[(size_t)e * CT + t] = p[e];
      if (p[e] > best) { best = p[e]; bi = e; }
    }
    gate[t] = best / (best + 1e-8f);
    int pos = atomicAdd(&cnt[bi], 1);
    toklist[bi * CT + pos] = t;
  }
}

// ---------------------------------------------------------------- load-balance loss; clears cnt
__global__ __launch_bounds__(1024) void k_lb(const float* __restrict__ probs,
                                             int* __restrict__ cnt,
                                             float* __restrict__ lbacc) {
  int tid = threadIdx.x;
  int e = tid >> 7, sub = tid & 127;
  float s = 0.f;
  for (int i = sub; i < CT; i += 128) s += probs[(size_t)e * CT + i];
#pragma unroll
  for (int o = 32; o; o >>= 1) s += __shfl_down(s, o, 64);
  __shared__ float red[16];
  __shared__ float pe[CE];
  if ((tid & 63) == 0) red[tid >> 6] = s;
  __syncthreads();
  if (tid < CE) {
    float rp = (red[tid * 2] + red[tid * 2 + 1]) * (1.f / CT);
    float eu = (float)cnt[tid] * (1.f / CT);
    pe[tid] = rp * eu;
    cnt[tid] = 0;
  }
  __syncthreads();
  if (tid == 0) {
    float lb = 0.f;
#pragma unroll
    for (int e2 = 0; e2 < CE; e2++) lb += pe[e2];
    lbacc[0] += (float)CE * lb;
  }
}

__global__ void k_write_lb(const float* __restrict__ lbacc, float* __restrict__ out) {
  out[(size_t)CT * CV] = lbacc[0] / (float)CL;
}

// ================================================================ launcher
extern "C" void kernel_launch(void* const* d_in, const int* in_sizes, int n_in,
                              void* d_out, int out_size, void* d_ws, size_t ws_size,
                              hipStream_t stream) {
  const int* ids = (const int*)d_in[0];
  const float* emb = (const float*)d_in[1];
  const float* pos = (const float*)d_in[2];
  const float* aiw = (const float*)d_in[3];
  const float* aib = (const float*)d_in[4];
  const float* aow = (const float*)d_in[5];
  const float* aob = (const float*)d_in[6];
  const float* l1g = (const float*)d_in[7];
  const float* l1b = (const float*)d_in[8];
  const float* gw = (const float*)d_in[9];
  const float* w1 = (const float*)d_in[10];
  const float* b1 = (const float*)d_in[11];
  const float* w2 = (const float*)d_in[12];
  const float* b2 = (const float*)d_in[13];
  const float* l2g = (const float*)d_in[14];
  const float* l2b = (const float*)d_in[15];
  const float* lnfg = (const float*)d_in[16];
  const float* lnfb = (const float*)d_in[17];
  const float* lmw = (const float*)d_in[18];
  float* out = (float*)d_out;

  char* ws = (char*)d_ws;
  size_t off = 0;
  auto alloc = [&](size_t bytes) { char* p = ws + off; off += (bytes + 255) & ~(size_t)255; return p; };
  float* x     = (float*)alloc((size_t)CT * CH * 4);
  u16*   x_bf  = (u16*)  alloc((size_t)CT * CH * 2);
  u16*   xf_bf = (u16*)  alloc((size_t)CT * CH * 2);
  float* qkv   = (float*)alloc((size_t)CT * CH3 * 4);
  float* sc    = (float*)alloc((size_t)CB * CNH * CS * CS * 4);
  float* attno = (float*)alloc((size_t)CT * CH * 4);
  float* tmp   = (float*)alloc((size_t)CT * CH * 4);
  float* hid   = (float*)alloc((size_t)CT * CFF * 4);
  float* probs = (float*)alloc((size_t)CE * CT * 4);
  float* gate  = (float*)alloc((size_t)CT * 4);
  float* lbacc = (float*)alloc(256);
  int*   cnt   = (int*)  alloc(CE * 4);
  int*   tokl  = (int*)  alloc((size_t)CE * CT * 4);
  // bf16 aliases (routing-safe layer-5 / LM-head buffers)
  u16* hid_bf = (u16*)hid;                  // overlay (L5 only)
  u16* wbuf1  = (u16*)sc;                   // overlay: sc free during L5 MoE
  u16* wbuf2  = wbuf1 + (size_t)CE * CFF * CH;
  u16* lmw_bf = wbuf2 + (size_t)CE * CFF * CH;

  dim3 blk(256);
  k_init<<<1, 64, 0, stream>>>(cnt, lbacc);
  k_embed<<<(CT * CH / 4) / 256, blk, 0, stream>>>(ids, emb, pos, x, x_bf);
  for (int l = 0; l < CL; l++) {
    // QKV projection (fp32)
    k_lin32<<<dim3(CH3 / 128, CT / 128), blk, 0, stream>>>(
        x, CH, aiw + (size_t)l * CH3 * CH, CH, CH, aib + (size_t)l * CH3, qkv, CH3);
    // attention (fp32)
    k_qk32<<<dim3(4, 4, CB * CNH), blk, 0, stream>>>(qkv, sc);
    k_softmax<<<CB * CNH * CS, blk, 0, stream>>>(sc);
    k_gemm_pv<<<dim3(1, CS / 64, CB * CNH), blk, 0, stream>>>(sc, qkv, attno);
    k_lin32<<<dim3(CH / 128, CT / 128), blk, 0, stream>>>(
        attno, CH, aow + (size_t)l * CH * CH, CH, CH, aob + (size_t)l * CH, tmp, CH);
    k_add_ln<<<CT, blk, 0, stream>>>(x, tmp, l1g + (size_t)l * CH, l1b + (size_t)l * CH, x, x_bf);
    // MoE routing (fp32 — routing-critical)
    k_gate<<<CT, blk, 0, stream>>>(x, gw + (size_t)l * CE * CH, probs, gate, cnt, tokl);
    if (l < CL - 1) {
      k_moe1_32<<<dim3(CFF / 128, CT / 128, CE), blk, 0, stream>>>(
          x, w1 + (size_t)l * CE * CFF * CH, b1 + (size_t)l * CE * CFF, cnt, tokl, hid);
      k_moe2_32<<<dim3(CH / 128, CT / 128, CE), blk, 0, stream>>>(
          hid, w2 + (size_t)l * CE * CH * CFF, b2 + (size_t)l * CE * CH, cnt, tokl, gate, tmp);
    } else {
      // layer 5 MoE is post-routing for all layers -> bf16 MFMA safe
      int n4a = CE * CFF * CH / 4;
      k_f2b<<<(n4a + 255) / 256, blk, 0, stream>>>(w1 + (size_t)l * CE * CFF * CH, wbuf1, n4a);
      k_f2b<<<(n4a + 255) / 256, blk, 0, stream>>>(w2 + (size_t)l * CE * CH * CFF, wbuf2, n4a);
      int n4l = CV * CH / 4;
      k_f2b<<<(n4l + 255) / 256, blk, 0, stream>>>(lmw, lmw_bf, n4l);
      k_moe1_bf<<<dim3(CFF / 128, CT / 128, CE), blk, 0, stream>>>(
          x_bf, wbuf1, b1 + (size_t)l * CE * CFF, cnt, tokl, hid_bf);
      k_moe2_bf<<<dim3(CH / 128, CT / 128, CE), blk, 0, stream>>>(
          hid_bf, wbuf2, b2 + (size_t)l * CE * CH, cnt, tokl, gate, tmp);
    }
    k_add_ln<<<CT, blk, 0, stream>>>(x, tmp, l2g + (size_t)l * CH, l2b + (size_t)l * CH, x, x_bf);
    k_lb<<<1, 1024, 0, stream>>>(probs, cnt, lbacc);
  }
  // final LN + LM head (bf16 MFMA)
  k_add_ln<<<CT, blk, 0, stream>>>(x, nullptr, lnfg, lnfb, tmp, xf_bf);
  k_linbf<<<dim3(CV / 128, CT / 128), blk, 0, stream>>>(xf_bf, CH, lmw_bf, CH, CH, nullptr, out, CV);
  k_write_lb<<<1, 1, 0, stream>>>(lbacc, out);
}